// Round 12
// baseline (1271.640 us; speedup 1.0000x reference)
//
#include <hip/hip_runtime.h>
#include <hip/hip_bf16.h>

// ---------------- problem constants ----------------
#define B_    32
#define L_    1024
#define D_    200          // real feature dim
#define DP    256          // padded feature dim (pad cols kept == 0 where it matters)
#define M_    (B_*L_)      // 32768 rows
#define NTOT  (M_*DP)      // 8388608 elems per activation buffer
#define NELEM 204800.f     // real elements per batch for layernorm (1024*200)
#define INVSCALE 0.07071067811865475f   // 1/sqrt(200)
#define LNEPS 1e-5f

typedef unsigned short u16;
typedef unsigned int   u32;
typedef long long      i64;
typedef __attribute__((ext_vector_type(8))) short bf16x8;   // 8 bf16 = 4 VGPRs
typedef __attribute__((ext_vector_type(4))) float f32x4;
typedef __attribute__((ext_vector_type(16))) float f32x16;  // 32x32 MFMA acc

__device__ __forceinline__ float bf2f(u32 lo16) {
    union { u32 i; float f; } v; v.i = lo16 << 16; return v.f;
}
__device__ __forceinline__ u16 f2bf(float f) {
    union { float f; u32 i; } v; v.f = f;
    u32 r = v.i + 0x7fffu + ((v.i >> 16) & 1u);   // RNE
    return (u16)(r >> 16);
}
__device__ __forceinline__ float ldf(const void* p, long i, int isbf) {
    return isbf ? bf2f(((const u16*)p)[i]) : ((const float*)p)[i];
}
__device__ __forceinline__ i64 ldtok(const void* p, long i, int isl64) {
    return isl64 ? ((const i64*)p)[i] : (i64)((const int*)p)[i];
}

// ============================================================
// runtime dtype detection (cheap insurance).
__global__ void k_dtype(const u16* __restrict__ e16, const u32* __restrict__ xw,
                        int* __restrict__ flag) {
    int t = threadIdx.x;            // 64 threads, one wave
    u32 u = e16[2*t];
    u32 ex = (u >> 7) & 0xFFu;
    int sane = (ex >= 0x60u && ex <= 0x87u) ? 1 : 0;
    unsigned long long m1 = __ballot(sane);
    int zhi = (xw[2*t + 1] == 0u) ? 1 : 0;
    unsigned long long m2 = __ballot(zhi);
    if (t == 0) {
        flag[0] = (__popcll(m1) >= 48) ? 1 : 0;
        flag[1] = (__popcll(m2) >= 48) ? 1 : 0;
    }
}

// ============================================================
// off[b] = number of zeros in x[b,:]
__global__ void k_off(const void* __restrict__ x, const int* __restrict__ flag,
                      int* __restrict__ off) {
    __shared__ int red[256];
    int b = blockIdx.x, t = threadIdx.x;
    int isl64 = flag[1];
    int cnt = 0;
    for (int l = t; l < L_; l += 256)
        cnt += (ldtok(x, (long)b*L_ + l, isl64) == 0) ? 1 : 0;
    red[t] = cnt; __syncthreads();
    for (int s = 128; s > 0; s >>= 1) {
        if (t < s) red[t] += red[t+s];
        __syncthreads();
    }
    if (t == 0) off[b] = red[0];
}

// ============================================================
// weights -> transposed bf16 Wt[n][k] (256x256, zero-padded), heads folded.
__global__ void k_wfold(const void* __restrict__ wqkv,
                        const void* __restrict__ wfuse,
                        const void* __restrict__ w1,
                        const void* __restrict__ w2,
                        const int* __restrict__ flag,
                        u16* __restrict__ tq, u16* __restrict__ tf,
                        u16* __restrict__ t1, u16* __restrict__ t2) {
    int idx = blockIdx.x*256 + threadIdx.x;          // over 256*256
    if (idx >= DP*DP) return;
    int isbf = flag[0];
    int n = idx / DP, k = idx % DP;
    float vq = 0.f, vf = 0.f, v1 = 0.f, v2 = 0.f;
    if (n < D_ && k < D_) {
        vq = ldf(wqkv, k*D_ + n, isbf);
        v1 = ldf(w1,   k*D_ + n, isbf);
        v2 = ldf(w2,   k*D_ + n, isbf);
        #pragma unroll
        for (int hh = 0; hh < 8; ++hh)
            vf += ldf(wfuse, (hh*D_ + k)*D_ + n, isbf);
    }
    tq[idx] = f2bf(vq); tf[idx] = f2bf(vf);
    t1[idx] = f2bf(v1); t2[idx] = f2bf(v2);
}

// biases -> padded f32 vectors; zero the LN partial accumulator; statA=identity.
__global__ void k_bfold(const void* __restrict__ bqkv, const void* __restrict__ bfuse,
                        const void* __restrict__ b1,   const void* __restrict__ b2,
                        const int* __restrict__ flag,
                        float* __restrict__ pq, float* __restrict__ pf,
                        float* __restrict__ p1, float* __restrict__ p2,
                        float* __restrict__ part, float* __restrict__ statA) {
    int c = threadIdx.x;             // 256
    int isbf = flag[0];
    float vq = 0.f, vf = 0.f, v1 = 0.f, v2 = 0.f;
    if (c < D_) {
        vq = ldf(bqkv, c, isbf); vf = ldf(bfuse, c, isbf);
        v1 = ldf(b1,   c, isbf); v2 = ldf(b2,   c, isbf);
    }
    pq[c] = vq; pf[c] = vf; p1[c] = v1; p2[c] = v2;
    if (c < 64) part[c] = 0.f;
    if (c < 32) { statA[2*c] = 0.f; statA[2*c+1] = 1.f; }  // identity LN for layer 0
}

// ============================================================
// h = embed[x] + positional ; f32 out only (consumers normalize+cast inline)
__global__ void k_embed(const void* __restrict__ x,
                        const void* __restrict__ emb,
                        const int* __restrict__ off,
                        const int* __restrict__ flag,
                        float* __restrict__ A) {
    int idx = blockIdx.x*256 + threadIdx.x;          // over NTOT
    int c = idx & 255;
    int l = (idx >> 8) & 1023;
    int b = idx >> 18;
    float v = 0.f;
    if (c < D_) {
        i64 tok = ldtok(x, (long)b*L_ + l, flag[1]);
        v = ldf(emb, (long)tok*D_ + c, flag[0]);
        int j = l - off[b];
        if (j >= 0) {
            float jf = (float)j;
            float angle = jf * __expf(-jf * 0.034538776394910684f);
            v += (c & 1) ? __sinf(angle) : __cosf(angle);
        }
    }
    A[idx] = v;
}

// ============================================================
// MFMA GEMM: C = act(A' * W + biasp) [+ Res', + LN partial stats]
//   LNA=1: A-source is raw f32 pre-LN buffer; normalize (x-mu)*inv inline,
//          convert to bf16 in registers.
//   RES=1: Res-source is raw f32 pre-LN buffer; residual = (Res-mu)*inv.
//          Out is f32 + per-batch sum/sumsq atomically added to part.
//   TRW=1: additionally write the bf16 result TRANSPOSED per batch into
//          Qt[b][col][key] (packed 8B stores, 4 rows/lane) -> kills k_tr.
// Wt staged to LDS [kc][n*8] with +8 u16 skew.
template<int ACT, int OBF, int RES, int LNA, int TRW>
__global__ __launch_bounds__(256) void k_gemm_m(const void* __restrict__ Asrc,
                                                const u16* __restrict__ Wt,
                                                const float* __restrict__ biasp,
                                                void* __restrict__ C,
                                                const float* __restrict__ Res,
                                                const float* __restrict__ rstat,
                                                float* __restrict__ part,
                                                u16* __restrict__ Qt) {
    __shared__ u16 wt3[32*1032];   // [kc][n*8], row stride 1032 u16
    const int t    = threadIdx.x;
    const int lane = t & 63;
    const int w    = t >> 6;
    const int quad = lane >> 4;
    const int l16  = lane & 15;
    const int r0   = blockIdx.x * 128;
    const int c0   = blockIdx.y * 128;

    float mu = 0.f, inv = 1.f;
    if (LNA || RES) {
        int batch = blockIdx.x >> 3;        // 128 rows/block, 1024 rows/batch
        mu  = rstat[2*batch];
        inv = rstat[2*batch + 1];
    }

    #pragma unroll
    for (int i = 0; i < 16; ++i) {
        int ci = t + i*256;            // 0..4095
        int n = ci >> 5, kc = ci & 31;
        *(uint4*)&wt3[kc*1032 + n*8] =
            *(const uint4*)(Wt + (size_t)(c0 + n)*DP + kc*8);
    }

    // A fragments: 2 row-blocks of 16 rows; K-chunks 0..6 (224..255 is pad)
    bf16x8 qa[2][7];
    #pragma unroll
    for (int rb = 0; rb < 2; ++rb) {
        size_t ro = (size_t)(r0 + w*32 + rb*16 + l16)*DP + quad*8;
        if (LNA) {
            const float* ar = (const float*)Asrc + ro;
            #pragma unroll
            for (int kk = 0; kk < 7; ++kk) {
                f32x4 va = *(const f32x4*)(ar + kk*32);
                f32x4 vb = *(const f32x4*)(ar + kk*32 + 4);
                bf16x8 q;
                q[0] = (short)f2bf((va[0]-mu)*inv);
                q[1] = (short)f2bf((va[1]-mu)*inv);
                q[2] = (short)f2bf((va[2]-mu)*inv);
                q[3] = (short)f2bf((va[3]-mu)*inv);
                q[4] = (short)f2bf((vb[0]-mu)*inv);
                q[5] = (short)f2bf((vb[1]-mu)*inv);
                q[6] = (short)f2bf((vb[2]-mu)*inv);
                q[7] = (short)f2bf((vb[3]-mu)*inv);
                qa[rb][kk] = q;
            }
        } else {
            const u16* ar = (const u16*)Asrc + ro;
            #pragma unroll
            for (int kk = 0; kk < 7; ++kk)
                qa[rb][kk] = *(const bf16x8*)(ar + kk*32);
        }
    }
    __syncthreads();

    f32x4 acc[2][8];
    #pragma unroll
    for (int rb = 0; rb < 2; ++rb)
        #pragma unroll
        for (int ct = 0; ct < 8; ++ct) acc[rb][ct] = (f32x4){0.f,0.f,0.f,0.f};

    #pragma unroll
    for (int ct = 0; ct < 8; ++ct) {
        #pragma unroll
        for (int kk = 0; kk < 7; ++kk) {
            bf16x8 vb = *(const bf16x8*)&wt3[(kk*4 + quad)*1032 + (ct*16 + l16)*8];
            acc[0][ct] = __builtin_amdgcn_mfma_f32_16x16x32_bf16(qa[0][kk], vb, acc[0][ct], 0,0,0);
            acc[1][ct] = __builtin_amdgcn_mfma_f32_16x16x32_bf16(qa[1][kk], vb, acc[1][ct], 0,0,0);
        }
    }

    float lsum = 0.f, lss = 0.f;
    #pragma unroll
    for (int ct = 0; ct < 8; ++ct) {
        int col = c0 + ct*16 + l16;
        float bv = biasp[col];
        #pragma unroll
        for (int rb = 0; rb < 2; ++rb) {
            u16 tq4[4];
            #pragma unroll
            for (int r = 0; r < 4; ++r) {
                int row = r0 + w*32 + rb*16 + quad*4 + r;
                float v = acc[rb][ct][r] + bv;
                if (ACT) v = fmaxf(v, 0.f);
                if (RES) {
                    v += (Res[(size_t)row*DP + col] - mu) * inv;
                    ((float*)C)[(size_t)row*DP + col] = v;
                    if (col < D_) { lsum += v; lss += v*v; }
                } else if (OBF) {
                    u16 hb = f2bf(v);
                    ((u16*)C)[(size_t)row*DP + col] = hb;
                    if (TRW) tq4[r] = hb;
                } else {
                    ((float*)C)[(size_t)row*DP + col] = v;
                }
            }
            if (TRW && OBF) {
                size_t batch = (size_t)(r0 >> 10);
                int key = (r0 & 1023) + w*32 + rb*16 + quad*4;
                *(uint2*)(Qt + batch*(size_t)(DP*L_) + (size_t)col*L_ + key)
                    = *(const uint2*)tq4;
            }
        }
    }
    if (RES) {
        __syncthreads();                    // wt3 reads done; reuse as scratch
        float* red = (float*)wt3;
        red[t] = lsum; red[256 + t] = lss;
        __syncthreads();
        for (int s = 128; s > 0; s >>= 1) {
            if (t < s) { red[t] += red[t+s]; red[256+t] += red[256+t+s]; }
            __syncthreads();
        }
        if (t == 0) {
            int batch = blockIdx.x >> 3;    // 128 rows per block, 1024 per batch
            atomicAdd(&part[2*batch],     red[0]);
            atomicAdd(&part[2*batch + 1], red[256]);
        }
    }
}

// ============================================================
// MFMA FLASH ATTENTION, 32x32 MFMA edition (no-max softmax: |s|<~3).
// R1..R11 post-mortem: the 70us plateau was LDS-THROUGHPUT-bound (4 waves x
// ~36 b128 LDS ops/iter ~= 90% of the CU's LDS pipe). Fix = halve LDS cost
// per output row with mfma_f32_32x32x16_bf16: per wave, 32 q-rows x 32 keys
// costs 13 QK reads + 2 pa + 14 PV reads (vs 28+ for 16 rows with 16x16).
// 4 waves x 32 rows = 128-row tile; grid 256 = 8 tiles x 32 batches
// (XCD-swizzled); KVBLK=32; R1-style reg staging (short live range over one
// barrier -- no spill per R11's V-path evidence). launch_bounds(256,1):
// 1 wave/SIMD may use up to 512 VGPRs -> oacc 112 + qa 52 fit w/o spill.
// C/D layout (HW-verified m74/m101): col=lane&31, row=(reg&3)+8*(reg>>2)
// +4*(lane>>5). A/B: row/col=lane&31, k=(lane>>5)*8+j (mirrors 16x16).
// All LDS pitches re-derived conflict-free: ks 264, vt 40, ps 40.
__global__ __launch_bounds__(256, 1) void k_attn_m(const u16* __restrict__ Qbf,
                                                   const u16* __restrict__ QbfT,
                                                   u16* __restrict__ O) {
    __shared__ u16 ks[32*264];     // [key][feat]   pitch 264 (bank-even)
    __shared__ u16 vt[256*40];     // [feat][key]   pitch 40  (bank-even)
    __shared__ u16 ps[128*40];     // [qrow][key]   wave-private 32-row bands
    const int t    = threadIdx.x;  // 0..255
    const int lane = t & 63;
    const int w    = t >> 6;       // 0..3
    const int l5   = lane >> 5;    // 0..1 (k-half)
    const int l31  = lane & 31;    // row/col within MFMA tile
    const int id   = blockIdx.x;   // 0..255
    const int xcd  = id & 7;
    const int ti   = (id >> 3) & 7;
    const int b    = ((id >> 6) << 3) | xcd;
    const int l0   = ti * 128;
    const u16* Qb  = Qbf  + (size_t)b*(L_*DP);
    const u16* QTb = QbfT + (size_t)b*(L_*DP);
    u16*       Ob  = O    + (size_t)b*(L_*DP);

    // Q fragments: 32 rows x 208 feats -> 13 k-chunks of 16
    bf16x8 qa[13];
    {
        const u16* qrow = Qb + (size_t)(l0 + w*32 + l31)*DP + l5*8;
        #pragma unroll
        for (int kc = 0; kc < 13; ++kc)
            qa[kc] = *(const bf16x8*)(qrow + kc*16);
    }
    f32x16 oacc[7];
    #pragma unroll
    for (int ft = 0; ft < 7; ++ft)
        #pragma unroll
        for (int i = 0; i < 16; ++i) oacc[ft][i] = 0.f;
    float l_acc[16];
    #pragma unroll
    for (int i = 0; i < 16; ++i) l_acc[i] = 0.f;

    for (int n0 = 0; n0 < L_; n0 += 32) {
        // stage K-tile + V-tile: loads issued pre-barrier (latency overlaps
        // barrier-A wait), regs->LDS after; live range = one barrier only.
        uint4 rk[4], rv[4];
        #pragma unroll
        for (int i = 0; i < 4; ++i) {
            int ci = t + i*256; int key = ci >> 5, g = ci & 31;
            rk[i] = *(const uint4*)(Qb + (size_t)(n0 + key)*DP + g*8);
        }
        #pragma unroll
        for (int i = 0; i < 4; ++i) {
            int ci = t + i*256; int feat = ci >> 2, g = ci & 3;
            rv[i] = *(const uint4*)(QTb + (size_t)feat*L_ + n0 + g*8);
        }
        __syncthreads();                   // A: prev-iter readers done
        #pragma unroll
        for (int i = 0; i < 4; ++i) {
            int ci = t + i*256; int key = ci >> 5, g = ci & 31;
            *(uint4*)&ks[key*264 + g*8] = rk[i];
        }
        #pragma unroll
        for (int i = 0; i < 4; ++i) {
            int ci = t + i*256; int feat = ci >> 2, g = ci & 3;
            *(uint4*)&vt[feat*40 + g*8] = rv[i];
        }
        __syncthreads();                   // B: staging visible

        // QK^T: one 32x32 score tile per wave (rows w*32.., keys n0..n0+31)
        f32x16 sc;
        #pragma unroll
        for (int i = 0; i < 16; ++i) sc[i] = 0.f;
        #pragma unroll
        for (int kc = 0; kc < 13; ++kc) {
            bf16x8 bb = *(const bf16x8*)&ks[l31*264 + kc*16 + l5*8];
            sc = __builtin_amdgcn_mfma_f32_32x32x16_bf16(qa[kc], bb, sc, 0, 0, 0);
        }
        // softmax numerators -> ps (wave-private band), row sums in l_acc
        #pragma unroll
        for (int i = 0; i < 16; ++i) {
            float p = __expf(sc[i] * INVSCALE);
            l_acc[i] += p;
            int row = (i & 3) + 8*(i >> 2) + 4*l5;
            ps[(w*32 + row)*40 + l31] = f2bf(p);
        }
        // PV: A = P (rows 0..31 of band, k = key), B = V[key][feat]
        bf16x8 pa0 = *(const bf16x8*)&ps[(w*32 + l31)*40 + l5*8];
        bf16x8 pa1 = *(const bf16x8*)&ps[(w*32 + l31)*40 + 16 + l5*8];
        #pragma unroll
        for (int ft = 0; ft < 7; ++ft) {
            bf16x8 vb0 = *(const bf16x8*)&vt[(ft*32 + l31)*40 + l5*8];
            bf16x8 vb1 = *(const bf16x8*)&vt[(ft*32 + l31)*40 + 16 + l5*8];
            oacc[ft] = __builtin_amdgcn_mfma_f32_32x32x16_bf16(pa0, vb0, oacc[ft], 0, 0, 0);
            oacc[ft] = __builtin_amdgcn_mfma_f32_32x32x16_bf16(pa1, vb1, oacc[ft], 0, 0, 0);
        }
    }
    // row-sum reduce across the 32 key-lanes (same l5 half holds same rows)
    #pragma unroll
    for (int i = 0; i < 16; ++i) {
        float v = l_acc[i];
        v += __shfl_xor(v, 1);
        v += __shfl_xor(v, 2);
        v += __shfl_xor(v, 4);
        v += __shfl_xor(v, 8);
        v += __shfl_xor(v, 16);
        l_acc[i] = 1.f / v;
    }
    #pragma unroll
    for (int ft = 0; ft < 7; ++ft)
        #pragma unroll
        for (int i = 0; i < 16; ++i) {
            int row = l0 + w*32 + (i & 3) + 8*(i >> 2) + 4*l5;
            Ob[(size_t)row*DP + ft*32 + l31] = f2bf(oacc[ft][i] * l_acc[i]);
        }
    #pragma unroll
    for (int i = 0; i < 16; ++i) {       // defined pads, feats 224..255
        int row = l0 + w*32 + (i & 3) + 8*(i >> 2) + 4*l5;
        Ob[(size_t)row*DP + 224 + l31] = 0;
    }
}

// ============================================================
// LN stats from fused partials; re-zero partials for the next layer.
__global__ void k_ln_stats(float* __restrict__ part, float* __restrict__ stats) {
    int b = threadIdx.x;
    if (b >= 32) return;
    float sum = part[2*b], ss = part[2*b+1];
    float mu  = sum / NELEM;
    float var = ss / NELEM - mu*mu;
    stats[b*2]   = mu;
    stats[b*2+1] = 1.f / sqrtf(var + LNEPS);
    part[2*b] = 0.f; part[2*b+1] = 0.f;
}

// ============================================================
// final copy, padded [M,256] raw f32 -> LN inline -> dense [M,200] f32 output.
__global__ void k_out(const float* __restrict__ A, const float* __restrict__ stat,
                      const int* __restrict__ flag, float* __restrict__ out) {
    int idx = blockIdx.x*256 + threadIdx.x;         // over M_*D_
    if (idx >= M_*D_) return;
    int row = idx / D_;
    int c   = idx - row*D_;
    int b   = row >> 10;
    float v = (A[(size_t)row*DP + c] - stat[2*b]) * stat[2*b+1];
    if (!isfinite(v)) v = 1000.f + 64.f*flag[0] + 16.f*flag[1];
    out[idx] = v;
}

// ============================================================
extern "C" void kernel_launch(void* const* d_in, const int* in_sizes, int n_in,
                              void* d_out, int out_size, void* d_ws, size_t ws_size,
                              hipStream_t stream) {
    const void* x     = d_in[0];
    const void* emb   = d_in[1];
    const void* wqkv  = d_in[2];
    const void* bqkv  = d_in[3];
    const void* wfuse = d_in[4];
    const void* bfuse = d_in[5];
    const void* w1    = d_in[6];
    const void* b1    = d_in[7];
    const void* w2    = d_in[8];
    const void* b2    = d_in[9];

    // ws: Y0,Y1 raw pre-LN f32 (33.5 MB each); Qbf,QbfT(=Hbf),Cbf bf16
    // (16.8 MB each); 4 bf16 weight mats; f32 biases/stats. Total ~118 MB.
    float* Y0  = (float*)d_ws;
    float* Y1  = Y0 + NTOT;
    u16* Qbf   = (u16*)(Y1 + NTOT);
    u16* QbfT  = Qbf + NTOT;          // overlaid by Hbf after attention
    u16* Hbf   = QbfT;
    u16* Cbf   = QbfT + NTOT;
    u16* wtq   = Cbf + NTOT;
    u16* wtf   = wtq + DP*DP;
    u16* wt1   = wtf + DP*DP;
    u16* wt2   = wt1 + DP*DP;
    float* bqp = (float*)(wt2 + DP*DP);
    float* bfp = bqp + DP;
    float* b1p = bfp + DP;
    float* b2p = b1p + DP;
    float* part  = b2p + DP;          // 64 (LN partial sums, re-zeroed in flight)
    float* statA = part + 64;         // 64: stats of Y0 (identity before layer 0)
    float* statB = statA + 64;        // 64: stats of Y1
    int*   off   = (int*)(statB + 64);// 32
    int*   flag  = off + 32;          // 2

    k_dtype<<<1, 64, 0, stream>>>((const u16*)emb, (const u32*)x, flag);
    k_off  <<<32, 256, 0, stream>>>(x, flag, off);
    k_wfold<<<DP*DP/256, 256, 0, stream>>>(wqkv, wfuse, w1, w2, flag,
                                           wtq, wtf, wt1, wt2);
    k_bfold<<<1, 256, 0, stream>>>(bqkv, bfuse, b1, b2, flag,
                                   bqp, bfp, b1p, b2p, part, statA);
    k_embed<<<NTOT/256, 256, 0, stream>>>(x, emb, off, flag, Y0);

    for (int s = 0; s < 6; ++s) {
        // q = LN(Y0) @ w_qkv + b_qkv  (LN inline on A; bf16 out + transposed copy)
        k_gemm_m<0,1,0,1,1><<<dim3(M_/128, DP/128), 256, 0, stream>>>(
            Y0, wtq, bqp, Qbf, nullptr, statA, nullptr, QbfT);
        // c = softmax(q q^T / sqrt(200)) q   (bf16 out, XCD-swizzled, 32x32 MFMA)
        k_attn_m<<<256, 256, 0, stream>>>(Qbf, QbfT, Cbf);
        // Y1 = c @ wfuse_eff + b_fuse + LN(Y0)  (f32 out + LN partials)
        k_gemm_m<0,0,1,0,0><<<dim3(M_/128, DP/128), 256, 0, stream>>>(
            Cbf, wtf, bfp, Y1, Y0, statA, part, nullptr);
        k_ln_stats<<<1, 64, 0, stream>>>(part, statB);
        // mlp: relu(LN(Y1)@w1+b1)  (LN inline on A, bf16 out)
        k_gemm_m<1,1,0,1,0><<<dim3(M_/128, DP/128), 256, 0, stream>>>(
            Y1, wt1, b1p, Hbf, nullptr, statB, nullptr, nullptr);
        // Y0 = h@w2 + b2 + LN(Y1)  (f32 out + LN partials)
        k_gemm_m<0,0,1,0,0><<<dim3(M_/128, DP/128), 256, 0, stream>>>(
            Hbf, wt2, b2p, Y0, Y1, statB, part, nullptr);
        k_ln_stats<<<1, 64, 0, stream>>>(part, statA);
    }
    k_out<<<(M_*D_ + 255)/256, 256, 0, stream>>>(Y0, statA, flag, (float*)d_out);
}

// Round 13
// 931.469 us; speedup vs baseline: 1.3652x; 1.3652x over previous
//
#include <hip/hip_runtime.h>
#include <hip/hip_bf16.h>

// ---------------- problem constants ----------------
#define B_    32
#define L_    1024
#define D_    200          // real feature dim
#define DP    256          // padded feature dim (pad cols kept == 0 where it matters)
#define M_    (B_*L_)      // 32768 rows
#define NTOT  (M_*DP)      // 8388608 elems per activation buffer
#define NELEM 204800.f     // real elements per batch for layernorm (1024*200)
#define INVSCALE 0.07071067811865475f   // 1/sqrt(200)
#define LNEPS 1e-5f

typedef unsigned short u16;
typedef unsigned int   u32;
typedef long long      i64;
typedef __attribute__((ext_vector_type(8))) short bf16x8;   // 8 bf16 = 4 VGPRs
typedef __attribute__((ext_vector_type(4))) float f32x4;

__device__ __forceinline__ float bf2f(u32 lo16) {
    union { u32 i; float f; } v; v.i = lo16 << 16; return v.f;
}
__device__ __forceinline__ u16 f2bf(float f) {
    union { float f; u32 i; } v; v.f = f;
    u32 r = v.i + 0x7fffu + ((v.i >> 16) & 1u);   // RNE
    return (u16)(r >> 16);
}
__device__ __forceinline__ float ldf(const void* p, long i, int isbf) {
    return isbf ? bf2f(((const u16*)p)[i]) : ((const float*)p)[i];
}
__device__ __forceinline__ i64 ldtok(const void* p, long i, int isl64) {
    return isl64 ? ((const i64*)p)[i] : (i64)((const int*)p)[i];
}

// LN stats from raw per-batch partials (sum, sumsq)
__device__ __forceinline__ void stats_from(const float* rpart, int batch,
                                           float* mu, float* inv) {
    float sum = rpart[2*batch], ss = rpart[2*batch+1];
    float m = sum / NELEM;
    float var = ss / NELEM - m*m;
    *mu = m; *inv = rsqrtf(var + LNEPS);
}

// ============================================================
// runtime dtype detection (cheap insurance).
__global__ void k_dtype(const u16* __restrict__ e16, const u32* __restrict__ xw,
                        int* __restrict__ flag) {
    int t = threadIdx.x;            // 64 threads, one wave
    u32 u = e16[2*t];
    u32 ex = (u >> 7) & 0xFFu;
    int sane = (ex >= 0x60u && ex <= 0x87u) ? 1 : 0;
    unsigned long long m1 = __ballot(sane);
    int zhi = (xw[2*t + 1] == 0u) ? 1 : 0;
    unsigned long long m2 = __ballot(zhi);
    if (t == 0) {
        flag[0] = (__popcll(m1) >= 48) ? 1 : 0;
        flag[1] = (__popcll(m2) >= 48) ? 1 : 0;
    }
}

// ============================================================
// off[b] = number of zeros in x[b,:]
__global__ void k_off(const void* __restrict__ x, const int* __restrict__ flag,
                      int* __restrict__ off) {
    __shared__ int red[256];
    int b = blockIdx.x, t = threadIdx.x;
    int isl64 = flag[1];
    int cnt = 0;
    for (int l = t; l < L_; l += 256)
        cnt += (ldtok(x, (long)b*L_ + l, isl64) == 0) ? 1 : 0;
    red[t] = cnt; __syncthreads();
    for (int s = 128; s > 0; s >>= 1) {
        if (t < s) red[t] += red[t+s];
        __syncthreads();
    }
    if (t == 0) off[b] = red[0];
}

// ============================================================
// weights -> transposed bf16 Wt[n][k] (256x256, zero-padded), heads folded.
__global__ void k_wfold(const void* __restrict__ wqkv,
                        const void* __restrict__ wfuse,
                        const void* __restrict__ w1,
                        const void* __restrict__ w2,
                        const int* __restrict__ flag,
                        u16* __restrict__ tq, u16* __restrict__ tf,
                        u16* __restrict__ t1, u16* __restrict__ t2) {
    int idx = blockIdx.x*256 + threadIdx.x;          // over 256*256
    if (idx >= DP*DP) return;
    int isbf = flag[0];
    int n = idx / DP, k = idx % DP;
    float vq = 0.f, vf = 0.f, v1 = 0.f, v2 = 0.f;
    if (n < D_ && k < D_) {
        vq = ldf(wqkv, k*D_ + n, isbf);
        v1 = ldf(w1,   k*D_ + n, isbf);
        v2 = ldf(w2,   k*D_ + n, isbf);
        #pragma unroll
        for (int hh = 0; hh < 8; ++hh)
            vf += ldf(wfuse, (hh*D_ + k)*D_ + n, isbf);
    }
    tq[idx] = f2bf(vq); tf[idx] = f2bf(vf);
    t1[idx] = f2bf(v1); t2[idx] = f2bf(v2);
}

// biases -> padded f32 vectors; zero ALL 12 LN partial accumulators (768 f).
__global__ void k_bfold(const void* __restrict__ bqkv, const void* __restrict__ bfuse,
                        const void* __restrict__ b1,   const void* __restrict__ b2,
                        const int* __restrict__ flag,
                        float* __restrict__ pq, float* __restrict__ pf,
                        float* __restrict__ p1, float* __restrict__ p2,
                        float* __restrict__ parts) {
    int c = threadIdx.x;             // 256
    int isbf = flag[0];
    float vq = 0.f, vf = 0.f, v1 = 0.f, v2 = 0.f;
    if (c < D_) {
        vq = ldf(bqkv, c, isbf); vf = ldf(bfuse, c, isbf);
        v1 = ldf(b1,   c, isbf); v2 = ldf(b2,   c, isbf);
    }
    pq[c] = vq; pf[c] = vf; p1[c] = v1; p2[c] = v2;
    parts[c] = 0.f; parts[c + 256] = 0.f; parts[c + 512] = 0.f;   // 12*64=768
}

// ============================================================
// h = embed[x] + positional ; f32 out only (consumers normalize+cast inline)
__global__ void k_embed(const void* __restrict__ x,
                        const void* __restrict__ emb,
                        const int* __restrict__ off,
                        const int* __restrict__ flag,
                        float* __restrict__ A) {
    int idx = blockIdx.x*256 + threadIdx.x;          // over NTOT
    int c = idx & 255;
    int l = (idx >> 8) & 1023;
    int b = idx >> 18;
    float v = 0.f;
    if (c < D_) {
        i64 tok = ldtok(x, (long)b*L_ + l, flag[1]);
        v = ldf(emb, (long)tok*D_ + c, flag[0]);
        int j = l - off[b];
        if (j >= 0) {
            float jf = (float)j;
            float angle = jf * __expf(-jf * 0.034538776394910684f);
            v += (c & 1) ? __sinf(angle) : __cosf(angle);
        }
    }
    A[idx] = v;
}

// ============================================================
// MFMA GEMM: C = act(A' * W + biasp) [+ Res', + LN partial stats]
//   LNA=1: A-source is raw f32 pre-LN buffer; normalize (x-mu)*inv inline.
//   RES=1: residual = (Res-mu)*inv; f32 out + batch sum/sumsq -> opart.
//   LNI=1: identity stats (layer-0 h is un-normalized) -- skips rpart read.
//   TRW=1: also write bf16 result TRANSPOSED per batch (kills k_tr).
// Stats are computed from RAW partials (rpart) inline -- k_ln_stats removed.
template<int ACT, int OBF, int RES, int LNA, int TRW, int LNI>
__global__ __launch_bounds__(256) void k_gemm_m(const void* __restrict__ Asrc,
                                                const u16* __restrict__ Wt,
                                                const float* __restrict__ biasp,
                                                void* __restrict__ C,
                                                const float* __restrict__ Res,
                                                const float* __restrict__ rpart,
                                                float* __restrict__ opart,
                                                u16* __restrict__ Qt) {
    __shared__ u16 wt3[32*1032];   // [kc][n*8], row stride 1032 u16
    const int t    = threadIdx.x;
    const int lane = t & 63;
    const int w    = t >> 6;
    const int quad = lane >> 4;
    const int l16  = lane & 15;
    const int r0   = blockIdx.x * 128;
    const int c0   = blockIdx.y * 128;

    float mu = 0.f, inv = 1.f;
    if ((LNA || RES) && !LNI) {
        int batch = blockIdx.x >> 3;        // 128 rows/block, 1024 rows/batch
        stats_from(rpart, batch, &mu, &inv);
    }

    #pragma unroll
    for (int i = 0; i < 16; ++i) {
        int ci = t + i*256;            // 0..4095
        int n = ci >> 5, kc = ci & 31;
        *(uint4*)&wt3[kc*1032 + n*8] =
            *(const uint4*)(Wt + (size_t)(c0 + n)*DP + kc*8);
    }

    // A fragments: 2 row-blocks of 16 rows; K-chunks 0..6 (224..255 is pad)
    bf16x8 qa[2][7];
    #pragma unroll
    for (int rb = 0; rb < 2; ++rb) {
        size_t ro = (size_t)(r0 + w*32 + rb*16 + l16)*DP + quad*8;
        if (LNA) {
            const float* ar = (const float*)Asrc + ro;
            #pragma unroll
            for (int kk = 0; kk < 7; ++kk) {
                f32x4 va = *(const f32x4*)(ar + kk*32);
                f32x4 vb = *(const f32x4*)(ar + kk*32 + 4);
                bf16x8 q;
                q[0] = (short)f2bf((va[0]-mu)*inv);
                q[1] = (short)f2bf((va[1]-mu)*inv);
                q[2] = (short)f2bf((va[2]-mu)*inv);
                q[3] = (short)f2bf((va[3]-mu)*inv);
                q[4] = (short)f2bf((vb[0]-mu)*inv);
                q[5] = (short)f2bf((vb[1]-mu)*inv);
                q[6] = (short)f2bf((vb[2]-mu)*inv);
                q[7] = (short)f2bf((vb[3]-mu)*inv);
                qa[rb][kk] = q;
            }
        } else {
            const u16* ar = (const u16*)Asrc + ro;
            #pragma unroll
            for (int kk = 0; kk < 7; ++kk)
                qa[rb][kk] = *(const bf16x8*)(ar + kk*32);
        }
    }
    __syncthreads();

    f32x4 acc[2][8];
    #pragma unroll
    for (int rb = 0; rb < 2; ++rb)
        #pragma unroll
        for (int ct = 0; ct < 8; ++ct) acc[rb][ct] = (f32x4){0.f,0.f,0.f,0.f};

    #pragma unroll
    for (int ct = 0; ct < 8; ++ct) {
        #pragma unroll
        for (int kk = 0; kk < 7; ++kk) {
            bf16x8 vb = *(const bf16x8*)&wt3[(kk*4 + quad)*1032 + (ct*16 + l16)*8];
            acc[0][ct] = __builtin_amdgcn_mfma_f32_16x16x32_bf16(qa[0][kk], vb, acc[0][ct], 0,0,0);
            acc[1][ct] = __builtin_amdgcn_mfma_f32_16x16x32_bf16(qa[1][kk], vb, acc[1][ct], 0,0,0);
        }
    }

    float lsum = 0.f, lss = 0.f;
    #pragma unroll
    for (int ct = 0; ct < 8; ++ct) {
        int col = c0 + ct*16 + l16;
        float bv = biasp[col];
        #pragma unroll
        for (int rb = 0; rb < 2; ++rb) {
            u16 tq4[4];
            #pragma unroll
            for (int r = 0; r < 4; ++r) {
                int row = r0 + w*32 + rb*16 + quad*4 + r;
                float v = acc[rb][ct][r] + bv;
                if (ACT) v = fmaxf(v, 0.f);
                if (RES) {
                    v += (Res[(size_t)row*DP + col] - mu) * inv;
                    ((float*)C)[(size_t)row*DP + col] = v;
                    if (col < D_) { lsum += v; lss += v*v; }
                } else if (OBF) {
                    u16 hb = f2bf(v);
                    ((u16*)C)[(size_t)row*DP + col] = hb;
                    if (TRW) tq4[r] = hb;
                } else {
                    ((float*)C)[(size_t)row*DP + col] = v;
                }
            }
            if (TRW && OBF) {
                size_t batch = (size_t)(r0 >> 10);
                int key = (r0 & 1023) + w*32 + rb*16 + quad*4;
                *(uint2*)(Qt + batch*(size_t)(DP*L_) + (size_t)col*L_ + key)
                    = *(const uint2*)tq4;
            }
        }
    }
    if (RES) {
        __syncthreads();                    // wt3 reads done; reuse as scratch
        float* red = (float*)wt3;
        red[t] = lsum; red[256 + t] = lss;
        __syncthreads();
        for (int s = 128; s > 0; s >>= 1) {
            if (t < s) { red[t] += red[t+s]; red[256+t] += red[256+t+s]; }
            __syncthreads();
        }
        if (t == 0) {
            int batch = blockIdx.x >> 3;    // 128 rows per block, 1024 per batch
            atomicAdd(&opart[2*batch],     red[0]);
            atomicAdd(&opart[2*batch + 1], red[256]);
        }
    }
}

// ============================================================
// MFMA FLASH ATTENTION (no-max softmax: |s|<~3, exp safe). bf16 out.
// Measured-best structure (R3: 70.4us) restored verbatim after R6-R12
// redesigns all regressed: 2 waves x 32 q-rows (64-row tile), 128 threads,
// grid 512 -> 2 blocks/CU overlap; ps wave-private -> 2 barriers/iter.
// XCD-swizzled: a batch's 16 q-tiles share one XCD L2.
__global__ __launch_bounds__(128, 1) void k_attn_m(const u16* __restrict__ Qbf,
                                                   const u16* __restrict__ QbfT,
                                                   u16* __restrict__ O) {
    __shared__ u16 ks[32*264];     // [key][feat]   (stride 264: conflict-free)
    __shared__ u16 vt[256*40];     // [feat][key]   (stride 40: conflict-free)
    __shared__ u16 ps[64*40];      // [qrow][key]   (wave-private halves)
    const int t    = threadIdx.x;  // 0..127
    const int lane = t & 63;
    const int w    = t >> 6;       // 0..1
    const int quad = lane >> 4;
    const int l16  = lane & 15;
    const int id   = blockIdx.x;
    const int xcd  = id & 7;
    const int ti   = (id >> 3) & 15;
    const int b    = ((id >> 7) << 3) | xcd;
    const int l0   = ti * 64;
    const u16* Qb  = Qbf  + (size_t)b*(L_*DP);
    const u16* QTb = QbfT + (size_t)b*(L_*DP);
    u16*       Ob  = O    + (size_t)b*(L_*DP);

    bf16x8 qa[2][7];
    #pragma unroll
    for (int rb = 0; rb < 2; ++rb) {
        const u16* qrow = Qb + (size_t)(l0 + w*32 + rb*16 + l16)*DP + quad*8;
        #pragma unroll
        for (int kk = 0; kk < 7; ++kk)
            qa[rb][kk] = *(const bf16x8*)(qrow + kk*32);
    }
    f32x4 oacc[2][13];
    #pragma unroll
    for (int rb = 0; rb < 2; ++rb)
        #pragma unroll
        for (int ft = 0; ft < 13; ++ft) oacc[rb][ft] = (f32x4){0.f, 0.f, 0.f, 0.f};
    float l_acc[2][4] = {{0.f,0.f,0.f,0.f},{0.f,0.f,0.f,0.f}};

    for (int n0 = 0; n0 < L_; n0 += 32) {
        __syncthreads();                       // prior iter's ks/vt reads done
        #pragma unroll
        for (int i = 0; i < 8; ++i) {
            int ci = t + i*128;                // 0..1023
            int row = ci >> 5, g = ci & 31;
            *(uint4*)&ks[row*264 + g*8] =
                *(const uint4*)(Qb + (size_t)(n0+row)*DP + g*8);
        }
        #pragma unroll
        for (int i = 0; i < 8; ++i) {
            int ci = t + i*128;
            int feat = ci >> 2, g = ci & 3;
            *(uint4*)&vt[feat*40 + g*8] =
                *(const uint4*)(QTb + (size_t)feat*L_ + n0 + g*8);
        }
        __syncthreads();                       // staging visible
        #pragma unroll
        for (int ct = 0; ct < 2; ++ct) {
            f32x4 sc0 = (f32x4){0.f, 0.f, 0.f, 0.f};
            f32x4 sc1 = (f32x4){0.f, 0.f, 0.f, 0.f};
            #pragma unroll
            for (int kk = 0; kk < 7; ++kk) {
                bf16x8 bb = *(const bf16x8*)&ks[(ct*16 + l16)*264 + kk*32 + quad*8];
                sc0 = __builtin_amdgcn_mfma_f32_16x16x32_bf16(qa[0][kk], bb, sc0, 0, 0, 0);
                sc1 = __builtin_amdgcn_mfma_f32_16x16x32_bf16(qa[1][kk], bb, sc1, 0, 0, 0);
            }
            #pragma unroll
            for (int r = 0; r < 4; ++r) {
                float p0 = __expf(sc0[r] * INVSCALE);
                float p1 = __expf(sc1[r] * INVSCALE);
                l_acc[0][r] += p0;
                l_acc[1][r] += p1;
                ps[(w*32 +      quad*4 + r)*40 + ct*16 + l16] = f2bf(p0);
                ps[(w*32 + 16 + quad*4 + r)*40 + ct*16 + l16] = f2bf(p1);
            }
        }
        // ps rows [w*32, w*32+32) are wave-private: lgkmcnt ordering suffices.
        bf16x8 pa0 = *(const bf16x8*)&ps[(w*32      + l16)*40 + quad*8];
        bf16x8 pa1 = *(const bf16x8*)&ps[(w*32 + 16 + l16)*40 + quad*8];
        #pragma unroll
        for (int ft = 0; ft < 13; ++ft) {
            bf16x8 vb = *(const bf16x8*)&vt[(ft*16 + l16)*40 + quad*8];
            oacc[0][ft] = __builtin_amdgcn_mfma_f32_16x16x32_bf16(pa0, vb, oacc[0][ft], 0, 0, 0);
            oacc[1][ft] = __builtin_amdgcn_mfma_f32_16x16x32_bf16(pa1, vb, oacc[1][ft], 0, 0, 0);
        }
    }
    #pragma unroll
    for (int rb = 0; rb < 2; ++rb)
        #pragma unroll
        for (int r = 0; r < 4; ++r) {
            float v = l_acc[rb][r];
            v += __shfl_xor(v, 1);
            v += __shfl_xor(v, 2);
            v += __shfl_xor(v, 4);
            v += __shfl_xor(v, 8);
            l_acc[rb][r] = 1.f / v;
        }
    #pragma unroll
    for (int rb = 0; rb < 2; ++rb)
        #pragma unroll
        for (int r = 0; r < 4; ++r) {
            u16* orow = Ob + (size_t)(l0 + w*32 + rb*16 + quad*4 + r)*DP + l16;
            #pragma unroll
            for (int ft = 0; ft < 13; ++ft)
                orow[ft*16] = f2bf(oacc[rb][ft][r] * l_acc[rb][r]);
            orow[13*16] = 0; orow[14*16] = 0; orow[15*16] = 0;  // defined pads
        }
}

// ============================================================
// final copy, padded [M,256] raw f32 -> LN inline -> dense [M,200] f32 output.
__global__ void k_out(const float* __restrict__ A, const float* __restrict__ rpart,
                      const int* __restrict__ flag, float* __restrict__ out) {
    int idx = blockIdx.x*256 + threadIdx.x;         // over M_*D_
    if (idx >= M_*D_) return;
    int row = idx / D_;
    int c   = idx - row*D_;
    int b   = row >> 10;
    float mu, inv;
    stats_from(rpart, b, &mu, &inv);
    float v = (A[(size_t)row*DP + c] - mu) * inv;
    if (!isfinite(v)) v = 1000.f + 64.f*flag[0] + 16.f*flag[1];
    out[idx] = v;
}

// ============================================================
extern "C" void kernel_launch(void* const* d_in, const int* in_sizes, int n_in,
                              void* d_out, int out_size, void* d_ws, size_t ws_size,
                              hipStream_t stream) {
    const void* x     = d_in[0];
    const void* emb   = d_in[1];
    const void* wqkv  = d_in[2];
    const void* bqkv  = d_in[3];
    const void* wfuse = d_in[4];
    const void* bfuse = d_in[5];
    const void* w1    = d_in[6];
    const void* b1    = d_in[7];
    const void* w2    = d_in[8];
    const void* b2    = d_in[9];

    // ws: Y0,Y1 raw pre-LN f32 (33.5 MB each); Qbf,QbfT(=Hbf),Cbf bf16
    // (16.8 MB each); 4 bf16 weight mats; f32 biases + 12 LN partial bufs.
    float* Y0  = (float*)d_ws;
    float* Y1  = Y0 + NTOT;
    u16* Qbf   = (u16*)(Y1 + NTOT);
    u16* QbfT  = Qbf + NTOT;          // overlaid by Hbf after attention
    u16* Hbf   = QbfT;
    u16* Cbf   = QbfT + NTOT;
    u16* wtq   = Cbf + NTOT;
    u16* wtf   = wtq + DP*DP;
    u16* wt1   = wtf + DP*DP;
    u16* wt2   = wt1 + DP*DP;
    float* bqp = (float*)(wt2 + DP*DP);
    float* bfp = bqp + DP;
    float* b1p = bfp + DP;
    float* b2p = b1p + DP;
    float* parts = b2p + DP;          // 12 x 64 floats: [s*128 + 0..63]=Y1 stats
                                      //                 [s*128 + 64..127]=Y0 stats
    int*   off   = (int*)(parts + 768);   // 32
    int*   flag  = off + 32;              // 2

    k_dtype<<<1, 64, 0, stream>>>((const u16*)emb, (const u32*)x, flag);
    k_off  <<<32, 256, 0, stream>>>(x, flag, off);
    k_wfold<<<DP*DP/256, 256, 0, stream>>>(wqkv, wfuse, w1, w2, flag,
                                           wtq, wtf, wt1, wt2);
    k_bfold<<<1, 256, 0, stream>>>(bqkv, bfuse, b1, b2, flag,
                                   bqp, bfp, b1p, b2p, parts);
    k_embed<<<NTOT/256, 256, 0, stream>>>(x, emb, off, flag, Y0);

    const dim3 gg(M_/128, DP/128);
    for (int s = 0; s < 6; ++s) {
        float* pY1 = parts + s*128;        // stats accumulator for Y1 (this layer)
        float* pY0 = parts + s*128 + 64;   // stats accumulator for Y0 (this layer out)
        float* pY0prev = parts + (s-1)*128 + 64;   // valid for s>0

        // q = LN(Y0) @ w_qkv + b_qkv  (LN inline on A; bf16 out + transposed copy)
        if (s == 0)
            k_gemm_m<0,1,0,1,1,1><<<gg, 256, 0, stream>>>(
                Y0, wtq, bqp, Qbf, nullptr, nullptr, nullptr, QbfT);
        else
            k_gemm_m<0,1,0,1,1,0><<<gg, 256, 0, stream>>>(
                Y0, wtq, bqp, Qbf, nullptr, pY0prev, nullptr, QbfT);
        // c = softmax(q q^T / sqrt(200)) q   (bf16 out, XCD-swizzled)
        k_attn_m<<<512, 128, 0, stream>>>(Qbf, QbfT, Cbf);
        // Y1 = c @ wfuse_eff + b_fuse + LN(Y0)  (f32 out + raw LN partials)
        if (s == 0)
            k_gemm_m<0,0,1,0,0,1><<<gg, 256, 0, stream>>>(
                Cbf, wtf, bfp, Y1, Y0, nullptr, pY1, nullptr);
        else
            k_gemm_m<0,0,1,0,0,0><<<gg, 256, 0, stream>>>(
                Cbf, wtf, bfp, Y1, Y0, pY0prev, pY1, nullptr);
        // mlp: relu(LN(Y1)@w1+b1)  (LN inline on A, bf16 out)
        k_gemm_m<1,1,0,1,0,0><<<gg, 256, 0, stream>>>(
            Y1, wt1, b1p, Hbf, nullptr, pY1, nullptr, nullptr);
        // Y0 = h@w2 + b2 + LN(Y1)  (f32 out + raw LN partials)
        k_gemm_m<0,0,1,0,0,0><<<gg, 256, 0, stream>>>(
            Hbf, wt2, b2p, Y0, Y1, pY1, pY0, nullptr);
    }
    k_out<<<(M_*D_ + 255)/256, 256, 0, stream>>>(Y0, parts + 5*128 + 64,
                                                 flag, (float*)d_out);
}